// Round 2
// baseline (883.835 us; speedup 1.0000x reference)
//
#include <hip/hip_runtime.h>

// AttributeOperator: out[b] = ReLU(attr_ops[attrs[b]] @ obj_emb[objs[b]])
// B=2048, D=512, N_ATTRS=512. attr_ops is 512MB fp32 -> purely HBM-bound.
// Strategy: group samples by attribute so each used operator matrix is
// streamed from HBM exactly once (~506MB unique) instead of per-sample (2GB).

constexpr int B_SZ    = 2048;
constexpr int D_SZ    = 512;
constexpr int N_ATTRS = 512;
constexpr int SPLIT   = 2;                    // row-split per attr
constexpr int ROWS_PER_BLOCK = D_SZ / SPLIT;  // 256 rows per block
constexpr int THREADS = 256;                  // 4 waves x 64 rows each

__device__ __forceinline__ float wave_sum(float p) {
#pragma unroll
  for (int off = 32; off; off >>= 1) p += __shfl_xor(p, off);
  return p;
}

// Process one chunk of NS samples (NS = 4 or 8) against this block's row range.
template <int NS>
__device__ __forceinline__ void do_chunk(
    const int* __restrict__ s_idx, int s0, int cnt,
    const int* __restrict__ objs,
    const float* __restrict__ M,          // this attr's matrix base
    const float* __restrict__ obj_emb,
    float* __restrict__ out,
    int rowbase, int lane) {
  const int nthis = min(cnt - s0, NS);

  float4 ra[NS], rb[NS];
  int bi[NS];
#pragma unroll
  for (int s = 0; s < NS; ++s) {
    int si = s0 + s;
    if (si >= cnt) si = s0;  // clamp: compute garbage, never stored
    const int b = s_idx[si];
    bi[s] = b;
    const float* rep = obj_emb + (size_t)objs[b] * D_SZ;
    ra[s] = *(const float4*)(rep + 4 * lane);
    rb[s] = *(const float4*)(rep + D_SZ / 2 + 4 * lane);
  }

  float res[NS];
#pragma unroll 4
  for (int r = 0; r < 64; ++r) {
    const float* Mr = M + (size_t)(rowbase + r) * D_SZ;
    const float4 ma = *(const float4*)(Mr + 4 * lane);
    const float4 mb = *(const float4*)(Mr + D_SZ / 2 + 4 * lane);
#pragma unroll
    for (int s = 0; s < NS; ++s) {
      float p = ma.x * ra[s].x + ma.y * ra[s].y + ma.z * ra[s].z + ma.w * ra[s].w
              + mb.x * rb[s].x + mb.y * rb[s].y + mb.z * rb[s].z + mb.w * rb[s].w;
      p = wave_sum(p);
      if (lane == r) res[s] = p;   // lane r owns row rowbase+r -> coalesced store
    }
  }

#pragma unroll
  for (int s = 0; s < NS; ++s) {
    if (s < nthis)
      out[(size_t)bi[s] * D_SZ + rowbase + lane] = fmaxf(res[s], 0.0f);
  }
}

__global__ __launch_bounds__(THREADS) void attr_op_kernel(
    const int* __restrict__ attrs, const int* __restrict__ objs,
    const float* __restrict__ attr_ops, const float* __restrict__ obj_emb,
    float* __restrict__ out) {
  __shared__ int s_idx[B_SZ];
  __shared__ int s_cnt;

  const int attr = blockIdx.x >> 1;   // SPLIT == 2
  const int half = blockIdx.x & 1;

  if (threadIdx.x == 0) s_cnt = 0;
  __syncthreads();

  // Scan attrs[] (8KB, L2-hit) to collect this attribute's sample indices.
  for (int b = threadIdx.x; b < B_SZ; b += THREADS) {
    if (attrs[b] == attr) {
      int p = atomicAdd(&s_cnt, 1);
      s_idx[p] = b;
    }
  }
  __syncthreads();
  const int cnt = s_cnt;
  if (cnt == 0) return;

  const int lane = threadIdx.x & 63;
  const int wave = threadIdx.x >> 6;
  const int rowbase = half * ROWS_PER_BLOCK + wave * 64;  // 64 rows per wave
  const float* __restrict__ M = attr_ops + (size_t)attr * D_SZ * D_SZ;

  // Chunks of up to 8 samples; E[chunks] ~= 1.03 for Poisson(4) counts, so
  // each matrix is streamed ~once. 4-sample fast path keeps VGPRs low.
  for (int s0 = 0; s0 < cnt; s0 += 8) {
    if (cnt - s0 > 4)
      do_chunk<8>(s_idx, s0, cnt, objs, M, obj_emb, out, rowbase, lane);
    else
      do_chunk<4>(s_idx, s0, cnt, objs, M, obj_emb, out, rowbase, lane);
  }
}

extern "C" void kernel_launch(void* const* d_in, const int* in_sizes, int n_in,
                              void* d_out, int out_size, void* d_ws, size_t ws_size,
                              hipStream_t stream) {
  const int*   attrs    = (const int*)d_in[0];
  const int*   objs     = (const int*)d_in[1];
  const float* attr_ops = (const float*)d_in[2];
  const float* obj_emb  = (const float*)d_in[3];
  float*       out      = (float*)d_out;

  attr_op_kernel<<<N_ATTRS * SPLIT, THREADS, 0, stream>>>(
      attrs, objs, attr_ops, obj_emb, out);
}

// Round 3
// 852.737 us; speedup vs baseline: 1.0365x; 1.0365x over previous
//
#include <hip/hip_runtime.h>

// AttributeOperator: out[b] = ReLU(attr_ops[attrs[b]] @ obj_emb[objs[b]])
// B=2048, D=512, N_ATTRS=512. 512MB operator table -> HBM-bound.
// R2 lesson: per-(row,sample) 64-lane butterfly (3072 ds-swizzle/chunk) made
// the kernel LDS-pipe/latency-bound (363us, 9.6% HBM BW). New mapping:
// lane=(q,c): q=lane>>4 owns one of 4 samples, c=lane&15 owns 32 of 512 cols.
// Reduce is 4 shfl steps across 16 lanes for ALL 4 samples at once ->
// 256 cross-lane ops per chunk (12x fewer). Loads/stores stay coalesced.

constexpr int B_SZ    = 2048;
constexpr int D_SZ    = 512;
constexpr int N_ATTRS = 512;
constexpr int SPLIT   = 2;     // row-split per attr: block owns 256 rows
constexpr int THREADS = 256;   // 4 waves x 64 rows each

__global__ __launch_bounds__(THREADS) void attr_op_kernel(
    const int* __restrict__ attrs, const int* __restrict__ objs,
    const float* __restrict__ attr_ops, const float* __restrict__ obj_emb,
    float* __restrict__ out) {
  __shared__ int s_idx[B_SZ];
  __shared__ int s_cnt;

  const int attr = blockIdx.x >> 1;   // SPLIT == 2
  const int half = blockIdx.x & 1;

  if (threadIdx.x == 0) s_cnt = 0;
  __syncthreads();

  // Collect this attribute's sample indices (attrs[] is 8KB, L2-hit).
  for (int b = threadIdx.x; b < B_SZ; b += THREADS) {
    if (attrs[b] == attr) {
      int p = atomicAdd(&s_cnt, 1);
      s_idx[p] = b;
    }
  }
  __syncthreads();
  const int cnt = s_cnt;
  if (cnt == 0) return;

  const int lane = threadIdx.x & 63;
  const int wave = threadIdx.x >> 6;
  const int c = lane & 15;   // col-chunk: cols {p*128 + c*8 .. +7}, p=0..3
  const int q = lane >> 4;   // sample slot 0..3
  const int rowbase = half * (D_SZ / SPLIT) + wave * 64;  // 64 rows per wave
  const float* __restrict__ M = attr_ops + (size_t)attr * D_SZ * D_SZ;

  for (int s0 = 0; s0 < cnt; s0 += 4) {
    int si = s0 + q;
    const bool live = (si < cnt);
    if (!live) si = s0;            // clamp: duplicate compute, store masked
    const int b = s_idx[si];
    const float* rep = obj_emb + (size_t)objs[b] * D_SZ;

    // This lane's 32 v-elements for ITS sample (8 float4 = 32 VGPR).
    float4 va[4], vb[4];
#pragma unroll
    for (int p = 0; p < 4; ++p) {
      va[p] = *(const float4*)(rep + p * 128 + c * 8);
      vb[p] = *(const float4*)(rep + p * 128 + c * 8 + 4);
    }

    float res[4];
#pragma unroll
    for (int i = 0; i < 4; ++i) {      // result slot: rows i*16 + rr
      res[i] = 0.0f;
#pragma unroll 4
      for (int rr = 0; rr < 16; ++rr) {
        const float* Mr = M + (size_t)(rowbase + i * 16 + rr) * D_SZ;
        float a0 = 0.f, a1 = 0.f, a2 = 0.f, a3 = 0.f;  // 4 indep chains
#pragma unroll
        for (int p = 0; p < 4; ++p) {
          const float4 ma = *(const float4*)(Mr + p * 128 + c * 8);
          const float4 mb = *(const float4*)(Mr + p * 128 + c * 8 + 4);
          float t = (p & 1) ? a1 : a0;
          t += ma.x * va[p].x + ma.y * va[p].y + ma.z * va[p].z + ma.w * va[p].w;
          if (p & 1) a1 = t; else a0 = t;
          float u = (p & 1) ? a3 : a2;
          u += mb.x * vb[p].x + mb.y * vb[p].y + mb.z * vb[p].z + mb.w * vb[p].w;
          if (p & 1) a3 = u; else a2 = u;
        }
        float sum = (a0 + a1) + (a2 + a3);
        // Reduce across the 16 c-lanes only (masks stay inside 16 lanes);
        // every lane ends with the row-sum for ITS sample q.
        sum += __shfl_xor(sum, 1);
        sum += __shfl_xor(sum, 2);
        sum += __shfl_xor(sum, 4);
        sum += __shfl_xor(sum, 8);
        res[i] = (c == rr) ? sum : res[i];  // lane c keeps row i*16+c
      }
    }

    if (live) {
      float* o = out + (size_t)b * D_SZ + rowbase + c;
#pragma unroll
      for (int i = 0; i < 4; ++i)
        o[i * 16] = fmaxf(res[i], 0.0f);   // 16-float segments per q-group
    }
  }
}

extern "C" void kernel_launch(void* const* d_in, const int* in_sizes, int n_in,
                              void* d_out, int out_size, void* d_ws, size_t ws_size,
                              hipStream_t stream) {
  const int*   attrs    = (const int*)d_in[0];
  const int*   objs     = (const int*)d_in[1];
  const float* attr_ops = (const float*)d_in[2];
  const float* obj_emb  = (const float*)d_in[3];
  float*       out      = (float*)d_out;

  attr_op_kernel<<<N_ATTRS * SPLIT, THREADS, 0, stream>>>(
      attrs, objs, attr_ops, obj_emb, out);
}